// Round 14
// baseline (316.134 us; speedup 1.0000x reference)
//
#include <hip/hip_runtime.h>
#include <math.h>
#include <stdint.h>

#define K_DIM 8192     // S*DIM
#define D_DIM 2048
#define M_ROWS 8192
#define N_W 32         // W columns (only 24 used in H)
#define NC 24
#define KSPLIT 16      // grid.y; partial H per ksplit slice
#define KSB 16         // ksteps (of 32 k) per block
#define ROWS 16        // rows per block = one MFMA tile
#define THR 64         // ONE wave per block
#define DX 4           // X prefetch ring depth
#define DB 2           // B prefetch ring depth
#define REP 4          // grid.z work replication (MEASUREMENT: all z identical)

typedef short bf16x8 __attribute__((ext_vector_type(8)));
typedef float f32x4 __attribute__((ext_vector_type(4)));
union U32x4 { uint32_t u[4]; bf16x8 v; };

// wfrag (u16, W rne-bf16 hi-only): [ks(256)][tile(2)][lane(64)][e(8)] = 512 KB.
#define WFI(ks, tile) (((ks) * 2 + (tile)) * 64)   // bf16x8 units

// ---------------------------------------------------------------------------
// Kernel 0: prepack W -> rne bf16 B-fragments (once).
// ---------------------------------------------------------------------------
__global__ __launch_bounds__(256) void mhc_prepack_kernel(
    const float* __restrict__ W, unsigned short* __restrict__ wfrag)
{
    const int idx = blockIdx.x * 256 + threadIdx.x;   // 0 .. 262143
    const int k = idx >> 5, n = idx & 31;
    const float w = W[(size_t)k * N_W + n];
    const uint32_t u = __float_as_uint(w);
    const uint32_t r = u + 0x7FFFu + ((u >> 16) & 1u);   // round-nearest-even

    const int ks = k >> 5, kk = k & 31;
    const int lane = ((kk >> 3) << 4) | (n & 15);
    const int e = kk & 7;
    const int tile = n >> 4;
    wfrag[((size_t)WFI(ks, tile) + lane) * 8 + e] = (unsigned short)(r >> 16);
}

// ---------------------------------------------------------------------------
// Kernel 1: R13's gemm, replicated REP x via blockIdx.z for measurement.
// All z-blocks compute IDENTICAL work and store IDENTICAL fp32 values to the
// same part[] addresses (benign bit-deterministic race). This multiplies the
// gemm's duration ~4x so it (a) appears in the rocprof top-5 with counters,
// (b) lets total_R14 - total_R13 = 3*G isolate the gemm's true duration.
// ---------------------------------------------------------------------------
__global__ __launch_bounds__(THR) void mhc_gemm_kernel(
    const float* __restrict__ X, const unsigned short* __restrict__ wfrag,
    float* __restrict__ part)
{
    const int l = threadIdx.x;                 // lane 0..63
    const int rowbase = blockIdx.x * ROWS;
    const int ks0 = blockIdx.y * KSB;
    // blockIdx.z intentionally unused: z replicates identical work.

    const float4* __restrict__ Xg = reinterpret_cast<const float4*>(X);
    const bf16x8* __restrict__ wf = reinterpret_cast<const bf16x8*>(wfrag);

    const int arow = rowbase + (l & 15);
    const size_t xbase = (size_t)arow * (K_DIM / 4) + ((l >> 4) << 1);

    f32x4 c0 = {0.f, 0.f, 0.f, 0.f};
    f32x4 c1 = {0.f, 0.f, 0.f, 0.f};

    float4 px[DX][2];
    bf16x8 pb[DB][2];

#pragma unroll
    for (int i = 0; i < DX; ++i) {
        px[i][0] = Xg[xbase + (size_t)(ks0 + i) * 8];
        px[i][1] = Xg[xbase + (size_t)(ks0 + i) * 8 + 1];
    }
#pragma unroll
    for (int i = 0; i < DB; ++i) {
        pb[i][0] = wf[WFI(ks0 + i, 0) + l];
        pb[i][1] = wf[WFI(ks0 + i, 1) + l];
    }

#pragma unroll
    for (int i = 0; i < KSB; ++i) {            // fully unrolled: slots static
        const float4 xa = px[i & (DX - 1)][0];
        const float4 xb = px[i & (DX - 1)][1];
        const bf16x8 b0 = pb[i & (DB - 1)][0];
        const bf16x8 b1 = pb[i & (DB - 1)][1];

        if (i + DX < KSB) {
            px[i & (DX - 1)][0] = Xg[xbase + (size_t)(ks0 + i + DX) * 8];
            px[i & (DX - 1)][1] = Xg[xbase + (size_t)(ks0 + i + DX) * 8 + 1];
        }
        if (i + DB < KSB) {
            pb[i & (DB - 1)][0] = wf[WFI(ks0 + i + DB, 0) + l];
            pb[i & (DB - 1)][1] = wf[WFI(ks0 + i + DB, 1) + l];
        }

        float xs[8];
        xs[0] = xa.x; xs[1] = xa.y; xs[2] = xa.z; xs[3] = xa.w;
        xs[4] = xb.x; xs[5] = xb.y; xs[6] = xb.z; xs[7] = xb.w;

        U32x4 ah, al;
#pragma unroll
        for (int p = 0; p < 4; ++p) {
            const uint32_t u0 = __float_as_uint(xs[2 * p]);
            const uint32_t u1 = __float_as_uint(xs[2 * p + 1]);
            const float h0 = __uint_as_float(u0 & 0xFFFF0000u);
            const float h1 = __uint_as_float(u1 & 0xFFFF0000u);
            const uint32_t r0 = __float_as_uint(xs[2 * p] - h0);
            const uint32_t r1 = __float_as_uint(xs[2 * p + 1] - h1);
            ah.u[p] = (u1 & 0xFFFF0000u) | (u0 >> 16);
            al.u[p] = (r1 & 0xFFFF0000u) | (r0 >> 16);
        }

        c0 = __builtin_amdgcn_mfma_f32_16x16x32_bf16(ah.v, b0, c0, 0, 0, 0);
        c0 = __builtin_amdgcn_mfma_f32_16x16x32_bf16(al.v, b0, c0, 0, 0, 0);
        c1 = __builtin_amdgcn_mfma_f32_16x16x32_bf16(ah.v, b1, c1, 0, 0, 0);
        c1 = __builtin_amdgcn_mfma_f32_16x16x32_bf16(al.v, b1, c1, 0, 0, 0);
    }

    // ---- non-atomic partial store: part[by][row][col] ----
    float* prow = part + ((size_t)blockIdx.y * M_ROWS + rowbase) * NC;
    const int drow0 = (l >> 4) << 2;
    const int col = l & 15;
#pragma unroll
    for (int r = 0; r < 4; ++r)
        prow[(drow0 + r) * NC + col] = c0[r];
    if (col < 8) {
#pragma unroll
        for (int r = 0; r < 4; ++r)
            prow[(drow0 + r) * NC + 16 + col] = c1[r];
    }
}

// ---------------------------------------------------------------------------
// Kernel 2: reduce partials + params (transform + sinkhorn) + apply.
// One block per row.  (UNCHANGED from R13 for clean A/B subtraction.)
// ---------------------------------------------------------------------------
__global__ __launch_bounds__(256) void mhc_apply_kernel(
    const float* __restrict__ X, const float* __restrict__ part,
    const float* __restrict__ ab, float* __restrict__ out)
{
    __shared__ float pbuf[NC];
    const int row = blockIdx.x;
    const int t = threadIdx.x;

    if (t < 64) {
        const int lane = t;
        float pl = 0.f;
        if (lane < NC) {
#pragma unroll
            for (int j = 0; j < KSPLIT; ++j)
                pl += part[((size_t)j * M_ROWS + row) * NC + lane];
        }
        const float bias  = (lane < NC) ? ab[lane] : 0.f;
        const float scale = ab[(lane < 16) ? 24 : ((lane < 20) ? 25 : 26)];

        float vout;
        if (lane < 16) {
            vout = __expf(fmaf(scale, pl, bias));                 // exp(a_res*H+b)
        } else {
            vout = fmaf(scale, 1.f / (1.f + __expf(-pl)), bias);  // a*sigmoid(H)+b
        }

        // Sinkhorn on lanes 0..15: lane = s*4 + i.
        float p = vout;
        for (int it = 0; it < 20; ++it) {
            float rs = p + __shfl_xor(p, 1);
            rs += __shfl_xor(rs, 2);
            p = p / rs;
            float cs = p + __shfl_xor(p, 4);
            cs += __shfl_xor(cs, 8);
            p = p / cs;
        }
        if (lane < NC) pbuf[lane] = (lane < 16) ? p : vout;
    }
    __syncthreads();

    float hres[4][4], hpre[4], hpos[4];
#pragma unroll
    for (int i = 0; i < 16; ++i) hres[i >> 2][i & 3] = pbuf[i];
#pragma unroll
    for (int i = 0; i < 4; ++i) hpre[i] = pbuf[16 + i];
#pragma unroll
    for (int i = 0; i < 4; ++i) hpos[i] = pbuf[20 + i];

    const float4* __restrict__ Xr =
        reinterpret_cast<const float4*>(X + (size_t)row * K_DIM);
    float4* __restrict__ Or = reinterpret_cast<float4*>(out + (size_t)row * K_DIM);

#pragma unroll
    for (int q = 0; q < 2; ++q) {
        const int pos = t + q * 256;          // float4 index within a 2048-seg
        float4 xq[4];
#pragma unroll
        for (int i = 0; i < 4; ++i) xq[i] = Xr[i * (D_DIM / 4) + pos];

        float y[4];
#pragma unroll
        for (int e = 0; e < 4; ++e) {
            float s = 0.f;
#pragma unroll
            for (int i = 0; i < 4; ++i)
                s = fmaf(hpre[i], reinterpret_cast<const float*>(&xq[i])[e], s);
            y[e] = s;
        }

#pragma unroll
        for (int s = 0; s < 4; ++s) {
            float4 o;
            float* oe = reinterpret_cast<float*>(&o);
#pragma unroll
            for (int e = 0; e < 4; ++e) {
                float v = hpos[s] * y[e];
#pragma unroll
                for (int i = 0; i < 4; ++i)
                    v = fmaf(hres[s][i], reinterpret_cast<const float*>(&xq[i])[e], v);
                oe[e] = v;
            }
            Or[s * (D_DIM / 4) + pos] = o;
        }
    }
}

extern "C" void kernel_launch(void* const* d_in, const int* in_sizes, int n_in,
                              void* d_out, int out_size, void* d_ws, size_t ws_size,
                              hipStream_t stream) {
    const float* X  = (const float*)d_in[0];
    const float* W  = (const float*)d_in[1];
    const float* ab = (const float*)d_in[2];
    float* out = (float*)d_out;
    unsigned short* wfrag = (unsigned short*)d_ws;          // 524,288 B
    float* part = (float*)((char*)d_ws + 524288);           // + 12,582,912 B

    mhc_prepack_kernel<<<(K_DIM * N_W) / 256, 256, 0, stream>>>(W, wfrag);
    dim3 g1(M_ROWS / ROWS, KSPLIT, REP);
    mhc_gemm_kernel<<<g1, THR, 0, stream>>>(X, wfrag, part);
    mhc_apply_kernel<<<M_ROWS, 256, 0, stream>>>(X, part, ab, out);
}

// Round 15
// 164.816 us; speedup vs baseline: 1.9181x; 1.9181x over previous
//
#include <hip/hip_runtime.h>
#include <math.h>
#include <stdint.h>

#define K_DIM 8192     // S*DIM
#define D_DIM 2048
#define M_ROWS 8192
#define N_W 32         // W columns (only 24 used in H)
#define NC 24
#define KSPLIT 4       // grid.y; 2048 k per block
#define ROWS 16        // rows per block = one MFMA tile
#define THR 64         // ONE wave per block
#define CCOL 256       // cols per chunk (16 rows x 1KB runs = 16KB)
#define NCH 8          // chunks per block (8 x 256 = 2048 k)
#define KSC 8          // ksteps (32 k) per chunk

typedef short bf16x8 __attribute__((ext_vector_type(8)));
typedef float f32x4 __attribute__((ext_vector_type(4)));
union U32x4 { uint32_t u[4]; bf16x8 v; };

typedef const uint32_t __attribute__((address_space(1)))* gas_ptr;
typedef uint32_t __attribute__((address_space(3)))* las_ptr;

// wfrag (u16, W rne-bf16 hi-only): [ks(256)][tile(2)][lane(64)][e(8)] = 512 KB.
#define WFI(ks, tile) (((ks) * 2 + (tile)) * 64)   // bf16x8 units

// ---------------------------------------------------------------------------
// Kernel 0: prepack W -> rne bf16 B-fragments (once).
// k-map matches A-frag map: lane=((k&31)>>3)*16+(n&15), e=k&7 (same perm on
// both MFMA operands so it cancels; only C/D layout matters).
// ---------------------------------------------------------------------------
__global__ __launch_bounds__(256) void mhc_prepack_kernel(
    const float* __restrict__ W, unsigned short* __restrict__ wfrag)
{
    const int idx = blockIdx.x * 256 + threadIdx.x;   // 0 .. 262143
    const int k = idx >> 5, n = idx & 31;
    const float w = W[(size_t)k * N_W + n];
    const uint32_t u = __float_as_uint(w);
    const uint32_t r = u + 0x7FFFu + ((u >> 16) & 1u);   // round-nearest-even

    const int ks = k >> 5, kk = k & 31;
    const int lane = ((kk >> 3) << 4) | (n & 15);
    const int e = kk & 7;
    const int tile = n >> 4;
    wfrag[((size_t)WFI(ks, tile) + lane) * 8 + e] = (unsigned short)(r >> 16);
}

// ---------------------------------------------------------------------------
// Kernel 1: partial H via MFMA, H = Xhi@W + Xlo@W.  STREAMING layout fix:
// X is read in 1KB-CONTIGUOUS runs (one row-chunk per instruction) via
// global_load_lds -> LDS linear [16][256] tiles, double-buffered per wave.
// One wave per block; per chunk: {16 B-loads (L2)} -> {16 gll (next chunk)}
// -> s_waitcnt vmcnt(16) (drains this chunk's X + B in order) -> compute
// 8 ksteps x 4 MFMA from LDS. sched_barrier(0) fences pin the order (the
// compiler cannot see the gll->ds_read dependency).  No barriers, no atomics:
// partial store to part[ksplit]; apply reduces.
// C/D: D[row=(l>>4)*4+reg][col=l&15]  [HW-verified].
// ---------------------------------------------------------------------------
__global__ __launch_bounds__(THR) void mhc_gemm_kernel(
    const float* __restrict__ X, const unsigned short* __restrict__ wfrag,
    float* __restrict__ part)
{
    __shared__ __align__(16) float Xl[2][ROWS * CCOL];   // 2 x 16 KB
    const int l = threadIdx.x;
    const int rowbase = blockIdx.x * ROWS;
    const int colbase = blockIdx.y * (K_DIM / KSPLIT);
    const int ks00 = blockIdx.y * (K_DIM / KSPLIT / 32);

    const bf16x8* __restrict__ wf = reinterpret_cast<const bf16x8*>(wfrag);

    f32x4 c0 = {0.f, 0.f, 0.f, 0.f};
    f32x4 c1 = {0.f, 0.f, 0.f, 0.f};

    // ---- issue chunk 0's X loads (16 x 1KB contiguous) ----
#pragma unroll
    for (int r = 0; r < ROWS; ++r) {
        const float* src = X + (size_t)(rowbase + r) * K_DIM + colbase + l * 4;
        __builtin_amdgcn_global_load_lds((gas_ptr)src, (las_ptr)&Xl[0][r * CCOL],
                                         16, 0, 0);
    }

#pragma unroll
    for (int c = 0; c < NCH; ++c) {
        // ---- B-loads for chunk c (issued BEFORE next-chunk X: vmcnt order) --
        bf16x8 b0[KSC], b1[KSC];
#pragma unroll
        for (int s = 0; s < KSC; ++s) {
            const int ks = ks00 + c * KSC + s;
            b0[s] = wf[WFI(ks, 0) + l];
            b1[s] = wf[WFI(ks, 1) + l];
        }
        __builtin_amdgcn_sched_barrier(0);

        // ---- issue chunk c+1's X loads into the other buffer ----
        if (c + 1 < NCH) {
#pragma unroll
            for (int r = 0; r < ROWS; ++r) {
                const float* src = X + (size_t)(rowbase + r) * K_DIM
                                   + colbase + (c + 1) * CCOL + l * 4;
                __builtin_amdgcn_global_load_lds(
                    (gas_ptr)src, (las_ptr)&Xl[(c + 1) & 1][r * CCOL], 16, 0, 0);
            }
            __builtin_amdgcn_sched_barrier(0);
            asm volatile("s_waitcnt vmcnt(16)" ::: "memory");
        } else {
            __builtin_amdgcn_sched_barrier(0);
            asm volatile("s_waitcnt vmcnt(0)" ::: "memory");
        }
        __builtin_amdgcn_sched_barrier(0);   // rule #18: fence ds_read hoisting

        // ---- compute chunk c: 8 ksteps x (2 ds_read_b128 + pack + 4 MFMA) --
        const float* xt = &Xl[c & 1][(l & 15) * CCOL + ((l >> 4) << 3)];
#pragma unroll
        for (int s = 0; s < KSC; ++s) {
            const float4 xa = *reinterpret_cast<const float4*>(xt + s * 32);
            const float4 xb = *reinterpret_cast<const float4*>(xt + s * 32 + 4);
            float xs[8];
            xs[0] = xa.x; xs[1] = xa.y; xs[2] = xa.z; xs[3] = xa.w;
            xs[4] = xb.x; xs[5] = xb.y; xs[6] = xb.z; xs[7] = xb.w;

            U32x4 ah, al;
#pragma unroll
            for (int p = 0; p < 4; ++p) {
                const uint32_t u0 = __float_as_uint(xs[2 * p]);
                const uint32_t u1 = __float_as_uint(xs[2 * p + 1]);
                const float h0 = __uint_as_float(u0 & 0xFFFF0000u);
                const float h1 = __uint_as_float(u1 & 0xFFFF0000u);
                const uint32_t r0 = __float_as_uint(xs[2 * p] - h0);
                const uint32_t r1 = __float_as_uint(xs[2 * p + 1] - h1);
                ah.u[p] = (u1 & 0xFFFF0000u) | (u0 >> 16);
                al.u[p] = (r1 & 0xFFFF0000u) | (r0 >> 16);
            }

            c0 = __builtin_amdgcn_mfma_f32_16x16x32_bf16(ah.v, b0[s], c0, 0, 0, 0);
            c0 = __builtin_amdgcn_mfma_f32_16x16x32_bf16(al.v, b0[s], c0, 0, 0, 0);
            c1 = __builtin_amdgcn_mfma_f32_16x16x32_bf16(ah.v, b1[s], c1, 0, 0, 0);
            c1 = __builtin_amdgcn_mfma_f32_16x16x32_bf16(al.v, b1[s], c1, 0, 0, 0);
        }
    }

    // ---- non-atomic partial store: part[by][row][col] ----
    float* prow = part + ((size_t)blockIdx.y * M_ROWS + rowbase) * NC;
    const int drow0 = (l >> 4) << 2;
    const int col = l & 15;
#pragma unroll
    for (int r = 0; r < 4; ++r)
        prow[(drow0 + r) * NC + col] = c0[r];
    if (col < 8) {
#pragma unroll
        for (int r = 0; r < 4; ++r)
            prow[(drow0 + r) * NC + 16 + col] = c1[r];
    }
}

// ---------------------------------------------------------------------------
// Kernel 2: reduce partials + params (transform + sinkhorn) + apply.
// One block per row.
// ---------------------------------------------------------------------------
__global__ __launch_bounds__(256) void mhc_apply_kernel(
    const float* __restrict__ X, const float* __restrict__ part,
    const float* __restrict__ ab, float* __restrict__ out)
{
    __shared__ float pbuf[NC];
    const int row = blockIdx.x;
    const int t = threadIdx.x;

    if (t < 64) {
        const int lane = t;
        float pl = 0.f;
        if (lane < NC) {
#pragma unroll
            for (int j = 0; j < KSPLIT; ++j)
                pl += part[((size_t)j * M_ROWS + row) * NC + lane];
        }
        const float bias  = (lane < NC) ? ab[lane] : 0.f;
        const float scale = ab[(lane < 16) ? 24 : ((lane < 20) ? 25 : 26)];

        float vout;
        if (lane < 16) {
            vout = __expf(fmaf(scale, pl, bias));                 // exp(a_res*H+b)
        } else {
            vout = fmaf(scale, 1.f / (1.f + __expf(-pl)), bias);  // a*sigmoid(H)+b
        }

        // Sinkhorn on lanes 0..15: lane = s*4 + i.
        float p = vout;
        for (int it = 0; it < 20; ++it) {
            float rs = p + __shfl_xor(p, 1);
            rs += __shfl_xor(rs, 2);
            p = p / rs;
            float cs = p + __shfl_xor(p, 4);
            cs += __shfl_xor(cs, 8);
            p = p / cs;
        }
        if (lane < NC) pbuf[lane] = (lane < 16) ? p : vout;
    }
    __syncthreads();

    float hres[4][4], hpre[4], hpos[4];
#pragma unroll
    for (int i = 0; i < 16; ++i) hres[i >> 2][i & 3] = pbuf[i];
#pragma unroll
    for (int i = 0; i < 4; ++i) hpre[i] = pbuf[16 + i];
#pragma unroll
    for (int i = 0; i < 4; ++i) hpos[i] = pbuf[20 + i];

    const float4* __restrict__ Xr =
        reinterpret_cast<const float4*>(X + (size_t)row * K_DIM);
    float4* __restrict__ Or = reinterpret_cast<float4*>(out + (size_t)row * K_DIM);

#pragma unroll
    for (int q = 0; q < 2; ++q) {
        const int pos = t + q * 256;          // float4 index within a 2048-seg
        float4 xq[4];
#pragma unroll
        for (int i = 0; i < 4; ++i) xq[i] = Xr[i * (D_DIM / 4) + pos];

        float y[4];
#pragma unroll
        for (int e = 0; e < 4; ++e) {
            float s = 0.f;
#pragma unroll
            for (int i = 0; i < 4; ++i)
                s = fmaf(hpre[i], reinterpret_cast<const float*>(&xq[i])[e], s);
            y[e] = s;
        }

#pragma unroll
        for (int s = 0; s < 4; ++s) {
            float4 o;
            float* oe = reinterpret_cast<float*>(&o);
#pragma unroll
            for (int e = 0; e < 4; ++e) {
                float v = hpos[s] * y[e];
#pragma unroll
                for (int i = 0; i < 4; ++i)
                    v = fmaf(hres[s][i], reinterpret_cast<const float*>(&xq[i])[e], v);
                oe[e] = v;
            }
            Or[s * (D_DIM / 4) + pos] = o;
        }
    }
}

extern "C" void kernel_launch(void* const* d_in, const int* in_sizes, int n_in,
                              void* d_out, int out_size, void* d_ws, size_t ws_size,
                              hipStream_t stream) {
    const float* X  = (const float*)d_in[0];
    const float* W  = (const float*)d_in[1];
    const float* ab = (const float*)d_in[2];
    float* out = (float*)d_out;
    unsigned short* wfrag = (unsigned short*)d_ws;          // 524,288 B
    float* part = (float*)((char*)d_ws + 524288);           // + 3,145,728 B

    mhc_prepack_kernel<<<(K_DIM * N_W) / 256, 256, 0, stream>>>(W, wfrag);
    dim3 g1(M_ROWS / ROWS, KSPLIT);
    mhc_gemm_kernel<<<g1, THR, 0, stream>>>(X, wfrag, part);
    mhc_apply_kernel<<<M_ROWS, 256, 0, stream>>>(X, part, ab, out);
}